// Round 1
// baseline (63689.362 us; speedup 1.0000x reference)
//
#include <hip/hip_runtime.h>
#include <cmath>

// ---------------- constants ----------------
#define TDEC 250
#define EPS_A 1e-6f

struct GD {
  const float* A; int lda;
  const float* W; int K;
  float* O; int N; int njt; int nkt;
  int mode;                 // 0: direct A[64,lda]; 1: combine 4 parts_l + cbias
  const float* parts; const float* cbias;
  int store;                // 0: O[kti][64,N]; 2: mel scatter + frame
  const float* sbias;
  float* frame; float* dout; int t;
};

struct Prior { float v[11]; };

// ---------------- init ----------------
__global__ __launch_bounds__(256) void k_init(float* ws) {
  int idx = blockIdx.x * 256 + threadIdx.x;
  for (int i = idx; i < 230400; i += gridDim.x * 256) {
    float v = 0.f;
    if (i >= 25600 && i < 58368 && ((i - 25600) & 511) == 0) v = 1.f;  // alpha[:,0]=1
    ws[i] = v;
  }
}

// ---------------- generic tiled GEMM: out[64,N] (+ksplit partials) ----------------
__global__ __launch_bounds__(256) void k_gemm(GD ga, GD gb, int nb0) {
  bool first = (int)blockIdx.x < nb0;
  GD g = first ? ga : gb;
  int bid = first ? (int)blockIdx.x : ((int)blockIdx.x - nb0);
  int jti = bid % g.njt, kti = bid / g.njt;
  int j0 = jti * 32;
  int klen = g.K / g.nkt;
  int k0 = kti * klen;
  __shared__ float4 xs[64][16];
  __shared__ float4 wsb[32][16];
  int tid = threadIdx.x;
  int tj = tid & 7, tb = tid >> 3;
  float acc[2][4] = {{0.f,0.f,0.f,0.f},{0.f,0.f,0.f,0.f}};
  for (int kc = 0; kc < klen; kc += 64) {
    int kbase = k0 + kc;
#pragma unroll
    for (int it = 0; it < 4; ++it) {
      int q = tid + it * 256;
      int b = q >> 4, kq = q & 15;
      int kk = kbase + kq * 4;
      float4 v;
      if (g.mode == 0) {
        v = *(const float4*)(g.A + (size_t)b * g.lda + kk);
      } else {
        const float* P = g.parts;
        float4 p0 = *(const float4*)(P + ((size_t)0*64 + b) * 256 + kk);
        float4 p1 = *(const float4*)(P + ((size_t)1*64 + b) * 256 + kk);
        float4 p2 = *(const float4*)(P + ((size_t)2*64 + b) * 256 + kk);
        float4 p3 = *(const float4*)(P + ((size_t)3*64 + b) * 256 + kk);
        float4 bb4 = *(const float4*)(g.cbias + kk);
        v = make_float4(p0.x+p1.x+p2.x+p3.x+bb4.x, p0.y+p1.y+p2.y+p3.y+bb4.y,
                        p0.z+p1.z+p2.z+p3.z+bb4.z, p0.w+p1.w+p2.w+p3.w+bb4.w);
      }
      xs[b][kq ^ (b & 15)] = v;
    }
#pragma unroll
    for (int it = 0; it < 2; ++it) {
      int q = tid + it * 256;
      int j = q >> 4, kq = q & 15;
      int jj = j0 + j;
      float4 v = make_float4(0.f,0.f,0.f,0.f);
      if (jj < g.N) v = *(const float4*)(g.W + (size_t)jj * g.K + kbase + kq * 4);
      wsb[j][kq ^ (j >> 2)] = v;
    }
    __syncthreads();
    int b0 = tb * 2;
    int jr = tj * 4;
#pragma unroll
    for (int kq = 0; kq < 16; ++kq) {
      float4 x0 = xs[b0][kq ^ (b0 & 15)];
      float4 x1 = xs[b0 + 1][kq ^ ((b0 + 1) & 15)];
#pragma unroll
      for (int jj = 0; jj < 4; ++jj) {
        float4 w = wsb[jr + jj][kq ^ ((jr + jj) >> 2)];
        acc[0][jj] = fmaf(x0.x, w.x, fmaf(x0.y, w.y, fmaf(x0.z, w.z, fmaf(x0.w, w.w, acc[0][jj]))));
        acc[1][jj] = fmaf(x1.x, w.x, fmaf(x1.y, w.y, fmaf(x1.z, w.z, fmaf(x1.w, w.w, acc[1][jj]))));
      }
    }
    __syncthreads();
  }
#pragma unroll
  for (int bb = 0; bb < 2; ++bb) {
    int b = tb * 2 + bb;
#pragma unroll
    for (int jj = 0; jj < 4; ++jj) {
      int j = j0 + tj * 4 + jj;
      if (j < g.N) {
        float v = acc[bb][jj];
        if (g.store == 0) {
          g.O[((size_t)kti * 64 + b) * g.N + j] = v;
        } else {
          v += g.sbias[j];
          g.frame[b * 400 + j] = v;
          g.dout[(size_t)b * 100000 + (j / 5) * 1250 + g.t * 5 + (j % 5)] = v;
        }
      }
    }
  }
}

// ---------------- prenet (2 layers fused, one block per batch row) ----------------
__global__ __launch_bounds__(256) void k_prenet(const float* frame, const float* p1w, const float* p1b,
                                                const float* p2w, const float* p2b, float* xcat) {
  int b = blockIdx.x, tid = threadIdx.x;
  __shared__ __align__(16) float fr[400];
  __shared__ __align__(16) float h1s[256];
  for (int k = tid; k < 400; k += 256) fr[k] = frame[b * 400 + k];
  __syncthreads();
  {
    const float4* wr = (const float4*)(p1w + (size_t)tid * 400);
    float a = p1b[tid];
#pragma unroll 4
    for (int k4 = 0; k4 < 100; ++k4) {
      float4 w = wr[k4];
      float4 x = *(const float4*)(&fr[k4 * 4]);
      a = fmaf(w.x, x.x, fmaf(w.y, x.y, fmaf(w.z, x.z, fmaf(w.w, x.w, a))));
    }
    h1s[tid] = fmaxf(a, 0.f);
  }
  __syncthreads();
  if (tid < 128) {
    const float4* wr = (const float4*)(p2w + (size_t)tid * 256);
    float a = p2b[tid];
#pragma unroll 4
    for (int k4 = 0; k4 < 64; ++k4) {
      float4 w = wr[k4];
      float4 x = *(const float4*)(&h1s[k4 * 4]);
      a = fmaf(w.x, x.x, fmaf(w.y, x.y, fmaf(w.z, x.z, fmaf(w.w, x.w, a))));
    }
    xcat[b * 896 + 768 + tid] = fmaxf(a, 0.f);
  }
}

// ---------------- attention GRU gates + G-MLP ----------------
__global__ __launch_bounds__(256) void k_att_gates(const float* gip, const float* ghp,
    const float* abi, const float* abh, float* h_att, float* xl,
    const float* dWw, const float* dWb, const float* dVw, float* G) {
  int b = blockIdx.x, j = threadIdx.x;
  __shared__ __align__(16) float hs[256];
  __shared__ __align__(16) float g1s[128];
  float gr = 0, gz = 0, gn = 0;
#pragma unroll
  for (int p = 0; p < 7; ++p) {
    const float* base = gip + ((size_t)p * 64 + b) * 768;
    gr += base[j]; gz += base[j + 256]; gn += base[j + 512];
  }
  float hr = 0, hz = 0, hn = 0;
#pragma unroll
  for (int p = 0; p < 2; ++p) {
    const float* base = ghp + ((size_t)p * 64 + b) * 768;
    hr += base[j]; hz += base[j + 256]; hn += base[j + 512];
  }
  float r = 1.f / (1.f + expf(-(gr + abi[j] + hr + abh[j])));
  float z = 1.f / (1.f + expf(-(gz + abi[j + 256] + hz + abh[j + 256])));
  float n = tanhf(gn + abi[j + 512] + r * (hn + abh[j + 512]));
  float h = h_att[b * 256 + j];
  float hnew = (1.f - z) * n + z * h;
  h_att[b * 256 + j] = hnew;
  xl[b * 1024 + 768 + j] = hnew;
  hs[j] = hnew;
  __syncthreads();
  if (j < 128) {
    float a = dWb[j];
    const float4* wr = (const float4*)(dWw + (size_t)j * 256);
#pragma unroll 4
    for (int k4 = 0; k4 < 64; ++k4) {
      float4 w = wr[k4];
      float4 x = *(const float4*)(&hs[k4 * 4]);
      a = fmaf(w.x, x.x, fmaf(w.y, x.y, fmaf(w.z, x.z, fmaf(w.w, x.w, a))));
    }
    g1s[j] = tanhf(a);
  }
  __syncthreads();
  if (j < 168) {
    float a = 0.f;
    const float4* wr = (const float4*)(dVw + (size_t)j * 128);
#pragma unroll 4
    for (int k4 = 0; k4 < 32; ++k4) {
      float4 w = wr[k4];
      float4 x = *(const float4*)(&g1s[k4 * 4]);
      a = fmaf(w.x, x.x, fmaf(w.y, x.y, fmaf(w.z, x.z, fmaf(w.w, x.w, a))));
    }
    G[b * 168 + j] = a;
  }
}

// ---------------- energies: prior conv + static/dyn convs + tanh MLP ----------------
__global__ __launch_bounds__(256) void k_e(const float* alpha, const float* G,
    const float* dFw, const float* dUw, const float* dTw, const float* dTb_, const float* dvw,
    Prior pr, float* e) {
  int bb = blockIdx.x;
  int b = bb >> 2, s0 = (bb & 3) * 128;
  int tid = threadIdx.x;
  __shared__ float al[148];
  __shared__ float Gl[168];
  __shared__ float fL[128 * 9], gL[128 * 9];
  __shared__ float du[1024], dt[1024];
  __shared__ float dtb[128], dv[128], pl[128];
  __shared__ float es[2][128];
  for (int i = tid; i < 148; i += 256) {
    int sg = s0 - 10 + i;
    al[i] = (sg >= 0 && sg < 512) ? alpha[b * 512 + sg] : 0.f;
  }
  for (int i = tid; i < 168; i += 256) Gl[i] = G[b * 168 + i];
  for (int i = tid; i < 1024; i += 256) { du[i] = dUw[i]; dt[i] = dTw[i]; }
  if (tid < 128) { dtb[tid] = dTb_[tid]; dv[tid] = dvw[tid]; }
  __syncthreads();
  for (int q = tid; q < 1024; q += 256) {
    int sl = q >> 3, ch = q & 7;
    float fa = 0.f, gaa = 0.f;
    const float* dfr = dFw + ch * 21;
    const float* ggr = Gl + ch * 21;
#pragma unroll
    for (int k = 0; k < 21; ++k) {
      float a = al[sl + k];
      fa = fmaf(dfr[k], a, fa);
      gaa = fmaf(ggr[k], a, gaa);
    }
    fL[sl * 9 + ch] = fa; gL[sl * 9 + ch] = gaa;
  }
  if (tid < 128) {
    float p = 0.f;
#pragma unroll
    for (int k = 0; k < 11; ++k) p = fmaf(pr.v[k], al[tid + k], p);
    pl[tid] = p;
  }
  __syncthreads();
  int sl = tid & 127, half = tid >> 7;
  float f0[8], g0[8];
#pragma unroll
  for (int r = 0; r < 8; ++r) { f0[r] = fL[sl * 9 + r]; g0[r] = gL[sl * 9 + r]; }
  float acc = 0.f;
  for (int c = half * 64; c < half * 64 + 64; ++c) {
    float a = dtb[c];
    const float* duc = du + c * 8;
    const float* dtc = dt + c * 8;
#pragma unroll
    for (int r = 0; r < 8; ++r) a = fmaf(duc[r], f0[r], fmaf(dtc[r], g0[r], a));
    acc = fmaf(dv[c], tanhf(a), acc);
  }
  es[half][sl] = acc;
  __syncthreads();
  if (tid < 128) {
    e[b * 512 + s0 + tid] = es[0][tid] + es[1][tid] + logf(fmaxf(pl[tid], 1e-6f));
  }
}

// ---------------- softmax + sparse context ----------------
__global__ __launch_bounds__(256) void k_softmax_ctx(const float* e, float* alpha,
    const float* enc, float* xcat, float* xl) {
  int b = blockIdx.x, tid = threadIdx.x;
  __shared__ float red[4];
  __shared__ int wc[8];
  __shared__ float lv[512];
  __shared__ short li[512];
  float e0 = e[b * 512 + tid], e1 = e[b * 512 + 256 + tid];
  float m = fmaxf(e0, e1);
  for (int o = 32; o; o >>= 1) m = fmaxf(m, __shfl_xor(m, o));
  int lane = tid & 63, wv = tid >> 6;
  if (lane == 0) red[wv] = m;
  __syncthreads();
  m = fmaxf(fmaxf(red[0], red[1]), fmaxf(red[2], red[3]));
  float p0 = expf(e0 - m), p1 = expf(e1 - m);
  float s = p0 + p1;
  for (int o = 32; o; o >>= 1) s += __shfl_xor(s, o);
  __syncthreads();
  if (lane == 0) red[wv] = s;
  __syncthreads();
  float inv = 1.f / (red[0] + red[1] + red[2] + red[3]);
  float a0 = p0 * inv, a1 = p1 * inv;
  alpha[b * 512 + tid] = a0;
  alpha[b * 512 + 256 + tid] = a1;
  // deterministic compaction via ballot + prefix
  unsigned long long m0 = __ballot(a0 > EPS_A);
  unsigned long long m1 = __ballot(a1 > EPS_A);
  if (lane == 0) { wc[wv] = (int)__popcll(m0); wc[4 + wv] = (int)__popcll(m1); }
  __syncthreads();
  int base0 = 0;
  for (int w = 0; w < wv; ++w) base0 += wc[w];
  int totalA = wc[0] + wc[1] + wc[2] + wc[3];
  int base1 = totalA;
  for (int w = 0; w < wv; ++w) base1 += wc[4 + w];
  int n = totalA + wc[4] + wc[5] + wc[6] + wc[7];
  unsigned long long below = (1ull << lane) - 1ull;
  if (a0 > EPS_A) { int p = base0 + (int)__popcll(m0 & below); li[p] = (short)tid; lv[p] = a0; }
  if (a1 > EPS_A) { int p = base1 + (int)__popcll(m1 & below); li[p] = (short)(256 + tid); lv[p] = a1; }
  __syncthreads();
  const float* encb = enc + (size_t)b * 512 * 768;
  for (int d = tid; d < 768; d += 256) {
    float acc = 0.f;
    for (int i = 0; i < n; ++i) acc = fmaf(lv[i], encb[(size_t)li[i] * 768 + d], acc);
    xcat[b * 896 + d] = acc;
    xl[b * 1024 + d] = acc;
  }
}

// ---------------- decoder GRU gates + residual ----------------
__global__ __launch_bounds__(256) void k_gru_gates(const float* gip, const float* ghp,
    const float* bi, const float* bh, float* h_state,
    int xmode, const float* partsl, const float* lbias, const float* xdirect, float* xnext) {
  int b = blockIdx.x, j = threadIdx.x;
  float gr = 0, gz = 0, gn = 0, hr = 0, hz = 0, hn = 0;
#pragma unroll
  for (int p = 0; p < 2; ++p) {
    const float* gb = gip + ((size_t)p * 64 + b) * 768;
    const float* hb = ghp + ((size_t)p * 64 + b) * 768;
    gr += gb[j]; gz += gb[j + 256]; gn += gb[j + 512];
    hr += hb[j]; hz += hb[j + 256]; hn += hb[j + 512];
  }
  float r = 1.f / (1.f + expf(-(gr + bi[j] + hr + bh[j])));
  float z = 1.f / (1.f + expf(-(gz + bi[j + 256] + hz + bh[j + 256])));
  float n = tanhf(gn + bi[j + 512] + r * (hn + bh[j + 512]));
  float h = h_state[b * 256 + j];
  float hnew = (1.f - z) * n + z * h;
  h_state[b * 256 + j] = hnew;
  float x;
  if (xmode == 0) {
    x = lbias[j];
#pragma unroll
    for (int p = 0; p < 4; ++p) x += partsl[((size_t)p * 64 + b) * 256 + j];
  } else {
    x = xdirect[b * 256 + j];
  }
  xnext[b * 256 + j] = x + hnew;
}

// ---------------- host ----------------
extern "C" void kernel_launch(void* const* d_in, const int* in_sizes, int n_in,
                              void* d_out, int out_size, void* d_ws, size_t ws_size,
                              hipStream_t stream) {
  (void)in_sizes; (void)n_in; (void)out_size; (void)ws_size;
  const float* enc  = (const float*)d_in[0];
  const float* p1w  = (const float*)d_in[1];
  const float* p1b  = (const float*)d_in[2];
  const float* p2w  = (const float*)d_in[3];
  const float* p2b  = (const float*)d_in[4];
  const float* awi  = (const float*)d_in[5];
  const float* abi  = (const float*)d_in[6];
  const float* awh  = (const float*)d_in[7];
  const float* abh  = (const float*)d_in[8];
  const float* dWw  = (const float*)d_in[9];
  const float* dWb  = (const float*)d_in[10];
  const float* dVw  = (const float*)d_in[11];
  const float* dFw  = (const float*)d_in[12];
  const float* dUw  = (const float*)d_in[13];
  const float* dTw  = (const float*)d_in[14];
  const float* dTb  = (const float*)d_in[15];
  const float* dvw  = (const float*)d_in[16];
  const float* lw   = (const float*)d_in[17];
  const float* lb   = (const float*)d_in[18];
  const float* g1wi = (const float*)d_in[19];
  const float* g1bi = (const float*)d_in[20];
  const float* g1wh = (const float*)d_in[21];
  const float* g1bh = (const float*)d_in[22];
  const float* g2wi = (const float*)d_in[23];
  const float* g2bi = (const float*)d_in[24];
  const float* g2wh = (const float*)d_in[25];
  const float* g2bh = (const float*)d_in[26];
  const float* prw  = (const float*)d_in[27];
  const float* prb  = (const float*)d_in[28];

  float* ws = (float*)d_ws;
  float* frame   = ws + 0;        // 25600
  float* alpha   = ws + 25600;    // 32768
  float* xcat    = ws + 58368;    // 64*896  [ctx | pre]
  float* xl      = ws + 115712;   // 64*1024 [ctx | h_att]
  float* h_att   = ws + 181248;   // 16384
  float* h1      = ws + 197632;   // 16384
  float* h2      = ws + 214016;   // 16384
  float* Gbuf    = ws + 230400;   // 10752
  float* ebuf    = ws + 241152;   // 32768
  float* gi_p    = ws + 273920;   // 7*49152
  float* gh_p    = ws + 617984;   // 2*49152
  float* parts_l = ws + 716288;   // 4*16384
  float* gi1_p   = ws + 781824;   // 2*49152
  float* gh1_p   = ws + 880128;   // 2*49152
  float* x2      = ws + 978432;   // 16384
  float* x3      = ws + 994816;   // 16384

  // beta-binomial prior pmf (n=10, a=0.1, b=0.9), flipped
  Prior pr;
  {
    double aP = 0.1, bP = 0.9;
    double logB0 = lgamma(aP) + lgamma(bP) - lgamma(aP + bP);
    double pm[11];
    for (int k = 0; k <= 10; ++k) {
      double logC = lgamma(11.0) - lgamma(k + 1.0) - lgamma(11.0 - k);
      double logBt = lgamma(k + aP) + lgamma(10.0 - k + bP) - lgamma(10.0 + aP + bP);
      pm[k] = exp(logC + logBt - logB0);
    }
    for (int k = 0; k < 11; ++k) pr.v[k] = (float)pm[10 - k];
  }

  auto mk = [](const float* A, int lda, const float* W, int K, float* O, int N, int njt, int nkt,
               int mode, const float* parts, const float* cbias) {
    GD g; g.A = A; g.lda = lda; g.W = W; g.K = K; g.O = O; g.N = N; g.njt = njt; g.nkt = nkt;
    g.mode = mode; g.parts = parts; g.cbias = cbias; g.store = 0; g.sbias = nullptr;
    g.frame = nullptr; g.dout = nullptr; g.t = 0;
    return g;
  };

  k_init<<<256, 256, 0, stream>>>(ws);

  for (int t = 0; t < TDEC; ++t) {
    k_prenet<<<64, 256, 0, stream>>>(frame, p1w, p1b, p2w, p2b, xcat);

    GD gi = mk(xcat, 896, awi, 896, gi_p, 768, 24, 7, 0, nullptr, nullptr);
    GD gh = mk(h_att, 256, awh, 256, gh_p, 768, 24, 2, 0, nullptr, nullptr);
    k_gemm<<<216, 256, 0, stream>>>(gi, gh, 168);

    k_att_gates<<<64, 256, 0, stream>>>(gi_p, gh_p, abi, abh, h_att, xl, dWw, dWb, dVw, Gbuf);

    k_e<<<256, 256, 0, stream>>>(alpha, Gbuf, dFw, dUw, dTw, dTb, dvw, pr, ebuf);

    k_softmax_ctx<<<64, 256, 0, stream>>>(ebuf, alpha, enc, xcat, xl);

    GD gl = mk(xl, 1024, lw, 1024, parts_l, 256, 8, 4, 0, nullptr, nullptr);
    k_gemm<<<32, 256, 0, stream>>>(gl, gl, 32);

    GD i1  = mk(nullptr, 256, g1wi, 256, gi1_p, 768, 24, 2, 1, parts_l, lb);
    GD h1g = mk(h1, 256, g1wh, 256, gh1_p, 768, 24, 2, 0, nullptr, nullptr);
    k_gemm<<<96, 256, 0, stream>>>(i1, h1g, 48);

    k_gru_gates<<<64, 256, 0, stream>>>(gi1_p, gh1_p, g1bi, g1bh, h1, 0, parts_l, lb, nullptr, x2);

    GD i2  = mk(x2, 256, g2wi, 256, gi1_p, 768, 24, 2, 0, nullptr, nullptr);
    GD h2g = mk(h2, 256, g2wh, 256, gh1_p, 768, 24, 2, 0, nullptr, nullptr);
    k_gemm<<<96, 256, 0, stream>>>(i2, h2g, 48);

    k_gru_gates<<<64, 256, 0, stream>>>(gi1_p, gh1_p, g2bi, g2bh, h2, 1, nullptr, nullptr, x2, x3);

    GD go = mk(x3, 256, prw, 256, nullptr, 400, 13, 1, 0, nullptr, nullptr);
    go.store = 2; go.sbias = prb; go.frame = frame; go.dout = (float*)d_out; go.t = t;
    k_gemm<<<13, 256, 0, stream>>>(go, go, 13);
  }
}